// Round 5
// baseline (38.035 us; speedup 1.0000x reference)
//
#include <hip/hip_runtime.h>
#include <hip/hip_bf16.h>
#include <math.h>

// Problem constants: N=4, E=64, L=512, D=768
#define PN 4
#define PE 64
#define PL 512
#define PD 768
#define PK2 (2 * PD)        // 1536
#define PM (PN * PE)        // 256 rows

#define SPL 16              // L splits (chunks of 32)
#define EG  4               // entities per pool block
#define PTHR 192            // pool block threads (192*4 = 768 d-cols)
#define NPOOL (PN * (PE / EG) * SPL)   // 1024 pool blocks
#define NCVT  ((PD * PK2) / (PTHR * 8)) // 768 W-convert blocks

using bf16x8 = __attribute__((ext_vector_type(8))) short;
using f32x4  = __attribute__((ext_vector_type(4))) float;

static __device__ __forceinline__ unsigned short f2bf(float x) {
    unsigned int u = __float_as_uint(x);
    unsigned int r = (u + 0x7FFFu + ((u >> 16) & 1u)) >> 16;   // RNE
    return (unsigned short)r;
}

// ---------------------------------------------------------------------------
// pool_p1 v3: ballot-SGPR masks, no LDS, float4 per thread.
// Pool blocks (bid 0..1023): (n, e-group of 4, L-chunk of 32).
//   192 threads; thread owns d = tid*4 .. tid*4+3 (float4).
//   Masks are wave-uniform uint32 bitfields built via __ballot.
//   Per (l,e,d): sm = fmaf(s_mval, v, sm); mx = fmax(mx, v + s_bias)
//   where s_mval in {1,0}, s_bias in {0,-3e38} are scalar cselects.
// Convert blocks (bid 1024..1791): W f32 -> Wb bf16, 8 elems/thread.
// ---------------------------------------------------------------------------
__global__ __launch_bounds__(PTHR) void pool_p1(
    const float* __restrict__ doc,    // [N][L][D]
    const float* __restrict__ map,    // [N][E][L]
    const float* __restrict__ W,      // [768][1536]
    float* __restrict__ Pmax,         // [256][16][768]
    float* __restrict__ Psum,         // [256][16][768]
    unsigned short* __restrict__ Wb)  // [768][1536] bf16
{
    const int bid = blockIdx.x;
    const int tid = threadIdx.x;

    if (bid >= NPOOL) {
        // ---- W conversion blocks ----
        const size_t i = ((size_t)(bid - NPOOL) * PTHR + tid) * 8;
        const float4 a = *reinterpret_cast<const float4*>(W + i);
        const float4 c = *reinterpret_cast<const float4*>(W + i + 4);
        union { unsigned short s[8]; uint4 v; } r;
        r.s[0] = f2bf(a.x); r.s[1] = f2bf(a.y); r.s[2] = f2bf(a.z); r.s[3] = f2bf(a.w);
        r.s[4] = f2bf(c.x); r.s[5] = f2bf(c.y); r.s[6] = f2bf(c.z); r.s[7] = f2bf(c.w);
        *reinterpret_cast<uint4*>(Wb + i) = r.v;
        return;
    }

    const int n   = bid >> 8;         // 0..3
    const int rem = bid & 255;
    const int eg  = rem >> 4;         // 0..15
    const int s   = rem & 15;         // 0..15
    const int e0  = eg * EG;
    const int l0  = s * 32;
    const int lane = tid & 63;

    // wave-uniform 32-bit masks, one per entity (lanes 32..63 mirror 0..31)
    unsigned int mk[EG];
    #pragma unroll
    for (int e = 0; e < EG; ++e) {
        const float m = map[((size_t)n * PE + e0 + e) * PL + l0 + (lane & 31)];
        mk[e] = (unsigned int)__ballot(m != 0.0f);
    }

    const float* docp = doc + ((size_t)n * PL + l0) * PD + tid * 4;

    float4 mx[EG], sm[EG];
    #pragma unroll
    for (int e = 0; e < EG; ++e) {
        mx[e] = make_float4(-INFINITY, -INFINITY, -INFINITY, -INFINITY);
        sm[e] = make_float4(0.f, 0.f, 0.f, 0.f);
    }

    #pragma unroll 8
    for (int l = 0; l < 32; ++l) {
        const float4 v = *reinterpret_cast<const float4*>(docp + (size_t)l * PD);
        #pragma unroll
        for (int e = 0; e < EG; ++e) {
            const bool bit = (mk[e] >> l) & 1u;     // wave-uniform
            const float mval = bit ? 1.0f : 0.0f;   // s_cselect
            const float bias = bit ? 0.0f : -3.0e38f;
            sm[e].x = fmaf(mval, v.x, sm[e].x);
            sm[e].y = fmaf(mval, v.y, sm[e].y);
            sm[e].z = fmaf(mval, v.z, sm[e].z);
            sm[e].w = fmaf(mval, v.w, sm[e].w);
            mx[e].x = fmaxf(mx[e].x, v.x + bias);
            mx[e].y = fmaxf(mx[e].y, v.y + bias);
            mx[e].z = fmaxf(mx[e].z, v.z + bias);
            mx[e].w = fmaxf(mx[e].w, v.w + bias);
        }
    }

    #pragma unroll
    for (int e = 0; e < EG; ++e) {
        const size_t base = ((size_t)(n * PE + e0 + e) * SPL + s) * PD + tid * 4;
        *reinterpret_cast<float4*>(Pmax + base) = mx[e];
        *reinterpret_cast<float4*>(Psum + base) = sm[e];
    }
}

// ---------------------------------------------------------------------------
// pool_p2: fold 16 L-chunk partials -> Pb bf16 [256][1536] (max | mean).
// has_zero for entity (n,e) <=> lens < 512 (lens is exact mask sum, >=1).
// 192 blocks x 256 threads; thread handles one (ne, 4-d-col) group.
// ---------------------------------------------------------------------------
__global__ __launch_bounds__(256) void pool_p2(
    const float* __restrict__ Pmax,
    const float* __restrict__ Psum,
    const float* __restrict__ lens,   // [256]
    unsigned short* __restrict__ Pb)  // [256][1536]
{
    const int idx = blockIdx.x * 256 + threadIdx.x;   // 0..49151
    const int ne = idx / (PD / 4);
    const int d  = (idx - ne * (PD / 4)) * 4;

    float4 mx = make_float4(-INFINITY, -INFINITY, -INFINITY, -INFINITY);
    float4 s4 = make_float4(0.f, 0.f, 0.f, 0.f);
    #pragma unroll
    for (int s = 0; s < SPL; ++s) {
        const size_t o = ((size_t)ne * SPL + s) * PD + d;
        const float4 a = *reinterpret_cast<const float4*>(Pmax + o);
        const float4 b = *reinterpret_cast<const float4*>(Psum + o);
        mx.x = fmaxf(mx.x, a.x); mx.y = fmaxf(mx.y, a.y);
        mx.z = fmaxf(mx.z, a.z); mx.w = fmaxf(mx.w, a.w);
        s4.x += b.x; s4.y += b.y; s4.z += b.z; s4.w += b.w;
    }
    const float ln = lens[ne];
    if (ln < 511.5f) {                 // some mask entry is 0
        mx.x = fmaxf(mx.x, 0.f); mx.y = fmaxf(mx.y, 0.f);
        mx.z = fmaxf(mx.z, 0.f); mx.w = fmaxf(mx.w, 0.f);
    }
    const float inv = 1.0f / ln;

    union { unsigned short s[4]; uint2 v; } rm, rs;
    rm.s[0] = f2bf(mx.x); rm.s[1] = f2bf(mx.y);
    rm.s[2] = f2bf(mx.z); rm.s[3] = f2bf(mx.w);
    rs.s[0] = f2bf(s4.x * inv); rs.s[1] = f2bf(s4.y * inv);
    rs.s[2] = f2bf(s4.z * inv); rs.s[3] = f2bf(s4.w * inv);

    unsigned short* prow = Pb + (size_t)ne * PK2;
    *reinterpret_cast<uint2*>(prow + d)      = rm.v;
    *reinterpret_cast<uint2*>(prow + PD + d) = rs.v;
}

// ---------------------------------------------------------------------------
// GEMM via MFMA bf16 16x16x32, no LDS. out[r][d] = sum_k P[r][k]*W[d][k] + b[d]
// 768 single-wave blocks, one 16x16 tile each.
// ---------------------------------------------------------------------------
__global__ __launch_bounds__(64) void gemm_mfma(
    const unsigned short* __restrict__ Pb,  // [256][1536] bf16
    const unsigned short* __restrict__ Wb,  // [768][1536] bf16
    const float* __restrict__ b,            // [768]
    float* __restrict__ out)                // [256][768]
{
    const int lane = threadIdx.x;
    const int tile = blockIdx.x;             // 0..767
    const int rt = tile & 15;                // M tile
    const int ct = tile >> 4;                // N tile
    const int r0 = rt * 16, d0 = ct * 16;

    const int fr = lane & 15;
    const int kg = lane >> 4;

    const unsigned short* pA = Pb + (size_t)(r0 + fr) * PK2 + kg * 8;
    const unsigned short* pB = Wb + (size_t)(d0 + fr) * PK2 + kg * 8;

    f32x4 acc = {0.f, 0.f, 0.f, 0.f};
    #pragma unroll 8
    for (int k0 = 0; k0 < PK2; k0 += 32) {
        const bf16x8 a  = *reinterpret_cast<const bf16x8*>(pA + k0);
        const bf16x8 bb = *reinterpret_cast<const bf16x8*>(pB + k0);
        acc = __builtin_amdgcn_mfma_f32_16x16x32_bf16(a, bb, acc, 0, 0, 0);
    }

    const int c = d0 + fr;
    const float bias = b[c];
    #pragma unroll
    for (int j = 0; j < 4; ++j)
        out[(size_t)(r0 + kg * 4 + j) * PD + c] = acc[j] + bias;
}

// ===========================================================================
// Fallback path (R2, proven): convert_w + pool_kernel2 + gemm_mfma (3 MiB ws)
// ===========================================================================
__global__ __launch_bounds__(256) void convert_w(
    const float* __restrict__ W, unsigned short* __restrict__ Wb)
{
    const size_t i = ((size_t)blockIdx.x * 256 + threadIdx.x) * 8;
    const float4 a = *reinterpret_cast<const float4*>(W + i);
    const float4 c = *reinterpret_cast<const float4*>(W + i + 4);
    union { unsigned short s[8]; uint4 v; } r;
    r.s[0] = f2bf(a.x); r.s[1] = f2bf(a.y); r.s[2] = f2bf(a.z); r.s[3] = f2bf(a.w);
    r.s[4] = f2bf(c.x); r.s[5] = f2bf(c.y); r.s[6] = f2bf(c.z); r.s[7] = f2bf(c.w);
    *reinterpret_cast<uint4*>(Wb + i) = r.v;
}

__global__ __launch_bounds__(1024) void pool_kernel2(
    const float* __restrict__ doc, const float* __restrict__ map,
    const float* __restrict__ lens, unsigned short* __restrict__ Pb)
{
    __shared__ float psum[4][PD];
    __shared__ float pmax[4][PD];
    __shared__ int   zf[4];
    const int ne = blockIdx.x, n = ne >> 6, t = threadIdx.x;
    const int g = t >> 8, td = t & 255;
    const float* docn = doc + (size_t)n * PL * PD;
    const float* mrow = map + (size_t)ne * PL;
    float mx0=-INFINITY, mx1=-INFINITY, mx2=-INFINITY, s0=0.f, s1=0.f, s2=0.f;
    bool hz = false;
    const int l0 = g * (PL/4), l1 = l0 + (PL/4);
    for (int l = l0; l < l1; ++l) {
        const float m = mrow[l];
        if (m != 0.0f) {
            const float* dr = docn + (size_t)l * PD;
            const float a = dr[td], c = dr[td+256], e = dr[td+512];
            mx0=fmaxf(mx0,a); s0+=a; mx1=fmaxf(mx1,c); s1+=c; mx2=fmaxf(mx2,e); s2+=e;
        } else hz = true;
    }
    psum[g][td]=s0; pmax[g][td]=mx0;
    psum[g][td+256]=s1; pmax[g][td+256]=mx1;
    psum[g][td+512]=s2; pmax[g][td+512]=mx2;
    if (td == 0) zf[g] = hz ? 1 : 0;
    __syncthreads();
    if (t < PD) {
        const float s = psum[0][t]+psum[1][t]+psum[2][t]+psum[3][t];
        float mx = fmaxf(fmaxf(pmax[0][t],pmax[1][t]), fmaxf(pmax[2][t],pmax[3][t]));
        if (zf[0]|zf[1]|zf[2]|zf[3]) mx = fmaxf(mx, 0.f);
        const float invlen = 1.0f / lens[ne];
        unsigned short* prow = Pb + (size_t)ne * PK2;
        prow[t]      = f2bf(mx);
        prow[PD + t] = f2bf(s * invlen);
    }
}

__global__ __launch_bounds__(256) void fused_kernel(
    const float* __restrict__ doc, const float* __restrict__ map,
    const float* __restrict__ lens, const float* __restrict__ W,
    const float* __restrict__ b, float* __restrict__ out)
{
    __shared__ float Prow[PK2];
    const int ne = blockIdx.x, n = ne >> 6, t = threadIdx.x;
    const float* docn = doc + (size_t)n * PL * PD;
    const float* mrow = map + (size_t)ne * PL;
    float mx0=-INFINITY, mx1=-INFINITY, mx2=-INFINITY, s0=0.f, s1=0.f, s2=0.f;
    bool has_zero = false;
    for (int l = 0; l < PL; ++l) {
        const float m = mrow[l];
        if (m != 0.0f) {
            const float* dr = docn + (size_t)l * PD;
            const float a = dr[t], c = dr[t+256], e = dr[t+512];
            mx0=fmaxf(mx0,a); s0+=a; mx1=fmaxf(mx1,c); s1+=c; mx2=fmaxf(mx2,e); s2+=e;
        } else has_zero = true;
    }
    if (has_zero) { mx0=fmaxf(mx0,0.f); mx1=fmaxf(mx1,0.f); mx2=fmaxf(mx2,0.f); }
    const float invlen = 1.0f / lens[ne];
    Prow[t]=mx0; Prow[t+256]=mx1; Prow[t+512]=mx2;
    Prow[PD+t]=s0*invlen; Prow[PD+t+256]=s1*invlen; Prow[PD+t+512]=s2*invlen;
    __syncthreads();
    #pragma unroll
    for (int i = 0; i < 3; ++i) {
        const int d = t + i*256;
        const float* wrow = W + (size_t)d * PK2;
        float acc = 0.f;
        for (int k = 0; k < PK2; k += 4) {
            const float4 w = *reinterpret_cast<const float4*>(&wrow[k]);
            acc += Prow[k]*w.x + Prow[k+1]*w.y + Prow[k+2]*w.z + Prow[k+3]*w.w;
        }
        out[(size_t)ne * PD + d] = acc + b[d];
    }
}

extern "C" void kernel_launch(void* const* d_in, const int* in_sizes, int n_in,
                              void* d_out, int out_size, void* d_ws, size_t ws_size,
                              hipStream_t stream) {
    const float* doc  = (const float*)d_in[0];   // (4,512,768)
    const float* map  = (const float*)d_in[1];   // (4,64,512)
    const float* lens = (const float*)d_in[2];   // (4,64)
    const float* W    = (const float*)d_in[3];   // (768,1536)
    const float* b    = (const float*)d_in[4];   // (768,)
    float* out = (float*)d_out;                  // (4,64,768)

    const size_t part_bytes = (size_t)PM * SPL * PD * sizeof(float);     // 12.6 MiB each
    const size_t pb_bytes   = (size_t)PM * PK2 * sizeof(unsigned short); // 768 KiB
    const size_t wb_bytes   = (size_t)PD * PK2 * sizeof(unsigned short); // 2.25 MiB
    const size_t need_new   = 2 * part_bytes + pb_bytes + wb_bytes;      // ~28.2 MiB
    const size_t need_bf16  = pb_bytes + wb_bytes;                       // 3 MiB

    if (ws_size >= need_new) {
        float* Pmax = (float*)d_ws;
        float* Psum = (float*)((char*)d_ws + part_bytes);
        unsigned short* Pb = (unsigned short*)((char*)d_ws + 2 * part_bytes);
        unsigned short* Wb = (unsigned short*)((char*)d_ws + 2 * part_bytes + pb_bytes);
        pool_p1<<<dim3(NPOOL + NCVT), dim3(PTHR), 0, stream>>>(
            doc, map, W, Pmax, Psum, Wb);
        pool_p2<<<dim3(PM * (PD / 4) / 256), dim3(256), 0, stream>>>(Pmax, Psum, lens, Pb);
        gemm_mfma<<<dim3((PM / 16) * (PD / 16)), dim3(64), 0, stream>>>(Pb, Wb, b, out);
    } else if (ws_size >= need_bf16) {
        unsigned short* Pb = (unsigned short*)d_ws;
        unsigned short* Wb = (unsigned short*)((char*)d_ws + pb_bytes);
        convert_w<<<dim3((PD * PK2) / (256 * 8)), dim3(256), 0, stream>>>(W, Wb);
        pool_kernel2<<<dim3(PM), dim3(1024), 0, stream>>>(doc, map, lens, Pb);
        gemm_mfma<<<dim3((PM / 16) * (PD / 16)), dim3(64), 0, stream>>>(Pb, Wb, b, out);
    } else {
        fused_kernel<<<dim3(PM), dim3(256), 0, stream>>>(doc, map, lens, W, b, out);
    }
}

// Round 6
// 34.405 us; speedup vs baseline: 1.1055x; 1.1055x over previous
//
#include <hip/hip_runtime.h>
#include <hip/hip_bf16.h>
#include <math.h>

// Problem constants: N=4, E=64, L=512, D=768
#define PN 4
#define PE 64
#define PL 512
#define PD 768
#define PK2 (2 * PD)        // 1536
#define PM (PN * PE)        // 256 rows

#define SPL 16              // L splits (chunks of 32)
#define EG  8               // entities per pool block
#define DC  3               // d-chunks of 256
#define NPOOL (PN * (PE / EG) * SPL * DC)      // 1536 pool blocks
#define NCVT  ((PD * PK2) / (256 * 8))         // 576 W-convert blocks

using bf16x8 = __attribute__((ext_vector_type(8))) short;
using f32x4  = __attribute__((ext_vector_type(4))) float;

static __device__ __forceinline__ unsigned short f2bf(float x) {
    unsigned int u = __float_as_uint(x);
    unsigned int r = (u + 0x7FFFu + ((u >> 16) & 1u)) >> 16;   // RNE
    return (unsigned short)r;
}

// ---------------------------------------------------------------------------
// pool_p1 v4: ballot->SGPR masks, NO LDS, no syncs, scalar d-col per thread.
// Pool blocks (bid 0..1535): (n, e-group of 8, L-chunk of 32, d-chunk of 256).
//   256 threads; thread owns ONE d = dc*256 + tid.
//   Per (l,e): bit test on SGPR mask (SALU) -> mval in {0,1} (s_cselect).
//   cand = mval * v  == entity_states element EXACTLY (0 when masked out),
//   so max needs no has_zero fixup at all:  mx = fmax(mx, cand); sm += cand.
// Convert blocks (bid 1536..2111): W f32 -> Wb bf16, 8 elems/thread.
// ---------------------------------------------------------------------------
__global__ __launch_bounds__(256) void pool_p1(
    const float* __restrict__ doc,    // [N][L][D]
    const float* __restrict__ map,    // [N][E][L]
    const float* __restrict__ W,      // [768][1536]
    float* __restrict__ Pmax,         // [256][16][768]
    float* __restrict__ Psum,         // [256][16][768]
    unsigned short* __restrict__ Wb)  // [768][1536] bf16
{
    const int bid = blockIdx.x;
    const int tid = threadIdx.x;

    if (bid >= NPOOL) {
        // ---- W conversion blocks ----
        const size_t i = ((size_t)(bid - NPOOL) * 256 + tid) * 8;
        const float4 a = *reinterpret_cast<const float4*>(W + i);
        const float4 c = *reinterpret_cast<const float4*>(W + i + 4);
        union { unsigned short s[8]; uint4 v; } r;
        r.s[0] = f2bf(a.x); r.s[1] = f2bf(a.y); r.s[2] = f2bf(a.z); r.s[3] = f2bf(a.w);
        r.s[4] = f2bf(c.x); r.s[5] = f2bf(c.y); r.s[6] = f2bf(c.z); r.s[7] = f2bf(c.w);
        *reinterpret_cast<uint4*>(Wb + i) = r.v;
        return;
    }

    const int dc  = bid % DC;
    const int grp = bid / DC;         // (n, eg, s)
    const int s   = grp & 15;
    const int eg  = (grp >> 4) & 7;
    const int n   = grp >> 7;
    const int e0  = eg * EG;
    const int l0  = s * 32;
    const int lane = tid & 63;

    // wave-uniform 32-bit masks, one per entity; readfirstlane -> SGPR
    unsigned int mk[EG];
    #pragma unroll
    for (int e = 0; e < EG; ++e) {
        const float m = map[((size_t)n * PE + e0 + e) * PL + l0 + (lane & 31)];
        const unsigned long long bl = __ballot(m != 0.0f);
        mk[e] = (unsigned int)__builtin_amdgcn_readfirstlane((int)(unsigned int)bl);
    }

    const float* docp = doc + ((size_t)n * PL + l0) * PD + dc * 256 + tid;

    float mx[EG], sm[EG];
    #pragma unroll
    for (int e = 0; e < EG; ++e) { mx[e] = -INFINITY; sm[e] = 0.f; }

    #pragma unroll 8
    for (int l = 0; l < 32; ++l) {
        const float v = docp[(size_t)l * PD];
        #pragma unroll
        for (int e = 0; e < EG; ++e) {
            const float mval = ((mk[e] >> l) & 1u) ? 1.0f : 0.0f;  // s_cselect
            const float cand = mval * v;          // exact entity_states elem
            sm[e] += cand;
            mx[e] = fmaxf(mx[e], cand);
        }
    }

    #pragma unroll
    for (int e = 0; e < EG; ++e) {
        const size_t base = ((size_t)(n * PE + e0 + e) * SPL + s) * PD + dc * 256 + tid;
        Pmax[base] = mx[e];
        Psum[base] = sm[e];
    }
}

// ---------------------------------------------------------------------------
// pool_p2: fold 16 L-chunk partials -> Pb bf16 [256][1536] (max | mean).
// No has_zero fixup needed (pool_p1 candidates already include the zeros).
// 192 blocks x 256 threads; thread handles one (ne, 4-d-col) group.
// ---------------------------------------------------------------------------
__global__ __launch_bounds__(256) void pool_p2(
    const float* __restrict__ Pmax,
    const float* __restrict__ Psum,
    const float* __restrict__ lens,   // [256]
    unsigned short* __restrict__ Pb)  // [256][1536]
{
    const int idx = blockIdx.x * 256 + threadIdx.x;   // 0..49151
    const int ne = idx / (PD / 4);
    const int d  = (idx - ne * (PD / 4)) * 4;

    float4 mx = make_float4(-INFINITY, -INFINITY, -INFINITY, -INFINITY);
    float4 s4 = make_float4(0.f, 0.f, 0.f, 0.f);
    #pragma unroll
    for (int s = 0; s < SPL; ++s) {
        const size_t o = ((size_t)ne * SPL + s) * PD + d;
        const float4 a = *reinterpret_cast<const float4*>(Pmax + o);
        const float4 b = *reinterpret_cast<const float4*>(Psum + o);
        mx.x = fmaxf(mx.x, a.x); mx.y = fmaxf(mx.y, a.y);
        mx.z = fmaxf(mx.z, a.z); mx.w = fmaxf(mx.w, a.w);
        s4.x += b.x; s4.y += b.y; s4.z += b.z; s4.w += b.w;
    }
    const float inv = 1.0f / lens[ne];

    union { unsigned short s[4]; uint2 v; } rm, rs;
    rm.s[0] = f2bf(mx.x); rm.s[1] = f2bf(mx.y);
    rm.s[2] = f2bf(mx.z); rm.s[3] = f2bf(mx.w);
    rs.s[0] = f2bf(s4.x * inv); rs.s[1] = f2bf(s4.y * inv);
    rs.s[2] = f2bf(s4.z * inv); rs.s[3] = f2bf(s4.w * inv);

    unsigned short* prow = Pb + (size_t)ne * PK2;
    *reinterpret_cast<uint2*>(prow + d)      = rm.v;
    *reinterpret_cast<uint2*>(prow + PD + d) = rs.v;
}

// ---------------------------------------------------------------------------
// GEMM via MFMA bf16 16x16x32, K split 4 ways across 4 waves + LDS reduce.
// out[r][d] = sum_k P[r][k]*W[d][k] + b[d].  768 blocks, one 16x16 tile each.
// ---------------------------------------------------------------------------
__global__ __launch_bounds__(256) void gemm_mfma(
    const unsigned short* __restrict__ Pb,  // [256][1536] bf16
    const unsigned short* __restrict__ Wb,  // [768][1536] bf16
    const float* __restrict__ b,            // [768]
    float* __restrict__ out)                // [256][768]
{
    __shared__ f32x4 red[3][64];

    const int w    = threadIdx.x >> 6;
    const int lane = threadIdx.x & 63;
    const int tile = blockIdx.x;             // 0..767
    const int rt = tile & 15;                // M tile
    const int ct = tile >> 4;                // N tile
    const int r0 = rt * 16, d0 = ct * 16;

    const int fr = lane & 15;
    const int kg = lane >> 4;
    const int kb = w * (PK2 / 4);            // 384-wide K slice per wave

    const unsigned short* pA = Pb + (size_t)(r0 + fr) * PK2 + kb + kg * 8;
    const unsigned short* pB = Wb + (size_t)(d0 + fr) * PK2 + kb + kg * 8;

    f32x4 acc = {0.f, 0.f, 0.f, 0.f};
    #pragma unroll
    for (int k0 = 0; k0 < PK2 / 4; k0 += 32) {
        const bf16x8 a  = *reinterpret_cast<const bf16x8*>(pA + k0);
        const bf16x8 bb = *reinterpret_cast<const bf16x8*>(pB + k0);
        acc = __builtin_amdgcn_mfma_f32_16x16x32_bf16(a, bb, acc, 0, 0, 0);
    }

    if (w > 0) red[w - 1][lane] = acc;
    __syncthreads();
    if (w == 0) {
        acc += red[0][lane];
        acc += red[1][lane];
        acc += red[2][lane];
        const int c = d0 + fr;
        const float bias = b[c];
        #pragma unroll
        for (int j = 0; j < 4; ++j)
            out[(size_t)(r0 + kg * 4 + j) * PD + c] = acc[j] + bias;
    }
}

// ===========================================================================
// Fallback path (R2, proven): convert_w + pool_kernel2 + gemm_mfma1 (3 MiB ws)
// ===========================================================================
__global__ __launch_bounds__(256) void convert_w(
    const float* __restrict__ W, unsigned short* __restrict__ Wb)
{
    const size_t i = ((size_t)blockIdx.x * 256 + threadIdx.x) * 8;
    const float4 a = *reinterpret_cast<const float4*>(W + i);
    const float4 c = *reinterpret_cast<const float4*>(W + i + 4);
    union { unsigned short s[8]; uint4 v; } r;
    r.s[0] = f2bf(a.x); r.s[1] = f2bf(a.y); r.s[2] = f2bf(a.z); r.s[3] = f2bf(a.w);
    r.s[4] = f2bf(c.x); r.s[5] = f2bf(c.y); r.s[6] = f2bf(c.z); r.s[7] = f2bf(c.w);
    *reinterpret_cast<uint4*>(Wb + i) = r.v;
}

__global__ __launch_bounds__(64) void gemm_mfma1(
    const unsigned short* __restrict__ Pb, const unsigned short* __restrict__ Wb,
    const float* __restrict__ b, float* __restrict__ out)
{
    const int lane = threadIdx.x;
    const int tile = blockIdx.x;
    const int rt = tile & 15, ct = tile >> 4;
    const int r0 = rt * 16, d0 = ct * 16;
    const int fr = lane & 15, kg = lane >> 4;
    const unsigned short* pA = Pb + (size_t)(r0 + fr) * PK2 + kg * 8;
    const unsigned short* pB = Wb + (size_t)(d0 + fr) * PK2 + kg * 8;
    f32x4 acc = {0.f, 0.f, 0.f, 0.f};
    #pragma unroll 8
    for (int k0 = 0; k0 < PK2; k0 += 32) {
        const bf16x8 a  = *reinterpret_cast<const bf16x8*>(pA + k0);
        const bf16x8 bb = *reinterpret_cast<const bf16x8*>(pB + k0);
        acc = __builtin_amdgcn_mfma_f32_16x16x32_bf16(a, bb, acc, 0, 0, 0);
    }
    const int c = d0 + fr;
    const float bias = b[c];
    #pragma unroll
    for (int j = 0; j < 4; ++j)
        out[(size_t)(r0 + kg * 4 + j) * PD + c] = acc[j] + bias;
}

__global__ __launch_bounds__(1024) void pool_kernel2(
    const float* __restrict__ doc, const float* __restrict__ map,
    const float* __restrict__ lens, unsigned short* __restrict__ Pb)
{
    __shared__ float psum[4][PD];
    __shared__ float pmax[4][PD];
    __shared__ int   zf[4];
    const int ne = blockIdx.x, n = ne >> 6, t = threadIdx.x;
    const int g = t >> 8, td = t & 255;
    const float* docn = doc + (size_t)n * PL * PD;
    const float* mrow = map + (size_t)ne * PL;
    float mx0=-INFINITY, mx1=-INFINITY, mx2=-INFINITY, s0=0.f, s1=0.f, s2=0.f;
    bool hz = false;
    const int l0 = g * (PL/4), l1 = l0 + (PL/4);
    for (int l = l0; l < l1; ++l) {
        const float m = mrow[l];
        if (m != 0.0f) {
            const float* dr = docn + (size_t)l * PD;
            const float a = dr[td], c = dr[td+256], e = dr[td+512];
            mx0=fmaxf(mx0,a); s0+=a; mx1=fmaxf(mx1,c); s1+=c; mx2=fmaxf(mx2,e); s2+=e;
        } else hz = true;
    }
    psum[g][td]=s0; pmax[g][td]=mx0;
    psum[g][td+256]=s1; pmax[g][td+256]=mx1;
    psum[g][td+512]=s2; pmax[g][td+512]=mx2;
    if (td == 0) zf[g] = hz ? 1 : 0;
    __syncthreads();
    if (t < PD) {
        const float s = psum[0][t]+psum[1][t]+psum[2][t]+psum[3][t];
        float mx = fmaxf(fmaxf(pmax[0][t],pmax[1][t]), fmaxf(pmax[2][t],pmax[3][t]));
        if (zf[0]|zf[1]|zf[2]|zf[3]) mx = fmaxf(mx, 0.f);
        const float invlen = 1.0f / lens[ne];
        unsigned short* prow = Pb + (size_t)ne * PK2;
        prow[t]      = f2bf(mx);
        prow[PD + t] = f2bf(s * invlen);
    }
}

__global__ __launch_bounds__(256) void fused_kernel(
    const float* __restrict__ doc, const float* __restrict__ map,
    const float* __restrict__ lens, const float* __restrict__ W,
    const float* __restrict__ b, float* __restrict__ out)
{
    __shared__ float Prow[PK2];
    const int ne = blockIdx.x, n = ne >> 6, t = threadIdx.x;
    const float* docn = doc + (size_t)n * PL * PD;
    const float* mrow = map + (size_t)ne * PL;
    float mx0=-INFINITY, mx1=-INFINITY, mx2=-INFINITY, s0=0.f, s1=0.f, s2=0.f;
    bool has_zero = false;
    for (int l = 0; l < PL; ++l) {
        const float m = mrow[l];
        if (m != 0.0f) {
            const float* dr = docn + (size_t)l * PD;
            const float a = dr[t], c = dr[t+256], e = dr[t+512];
            mx0=fmaxf(mx0,a); s0+=a; mx1=fmaxf(mx1,c); s1+=c; mx2=fmaxf(mx2,e); s2+=e;
        } else has_zero = true;
    }
    if (has_zero) { mx0=fmaxf(mx0,0.f); mx1=fmaxf(mx1,0.f); mx2=fmaxf(mx2,0.f); }
    const float invlen = 1.0f / lens[ne];
    Prow[t]=mx0; Prow[t+256]=mx1; Prow[t+512]=mx2;
    Prow[PD+t]=s0*invlen; Prow[PD+t+256]=s1*invlen; Prow[PD+t+512]=s2*invlen;
    __syncthreads();
    #pragma unroll
    for (int i = 0; i < 3; ++i) {
        const int d = t + i*256;
        const float* wrow = W + (size_t)d * PK2;
        float acc = 0.f;
        for (int k = 0; k < PK2; k += 4) {
            const float4 w = *reinterpret_cast<const float4*>(&wrow[k]);
            acc += Prow[k]*w.x + Prow[k+1]*w.y + Prow[k+2]*w.z + Prow[k+3]*w.w;
        }
        out[(size_t)ne * PD + d] = acc + b[d];
    }
}

extern "C" void kernel_launch(void* const* d_in, const int* in_sizes, int n_in,
                              void* d_out, int out_size, void* d_ws, size_t ws_size,
                              hipStream_t stream) {
    const float* doc  = (const float*)d_in[0];   // (4,512,768)
    const float* map  = (const float*)d_in[1];   // (4,64,512)
    const float* lens = (const float*)d_in[2];   // (4,64)
    const float* W    = (const float*)d_in[3];   // (768,1536)
    const float* b    = (const float*)d_in[4];   // (768,)
    float* out = (float*)d_out;                  // (4,64,768)

    const size_t part_bytes = (size_t)PM * SPL * PD * sizeof(float);     // 12.6 MiB each
    const size_t pb_bytes   = (size_t)PM * PK2 * sizeof(unsigned short); // 768 KiB
    const size_t wb_bytes   = (size_t)PD * PK2 * sizeof(unsigned short); // 2.25 MiB
    const size_t need_new   = 2 * part_bytes + pb_bytes + wb_bytes;      // ~28.2 MiB
    const size_t need_bf16  = pb_bytes + wb_bytes;                       // 3 MiB

    if (ws_size >= need_new) {
        float* Pmax = (float*)d_ws;
        float* Psum = (float*)((char*)d_ws + part_bytes);
        unsigned short* Pb = (unsigned short*)((char*)d_ws + 2 * part_bytes);
        unsigned short* Wb = (unsigned short*)((char*)d_ws + 2 * part_bytes + pb_bytes);
        pool_p1<<<dim3(NPOOL + NCVT), dim3(256), 0, stream>>>(
            doc, map, W, Pmax, Psum, Wb);
        pool_p2<<<dim3(PM * (PD / 4) / 256), dim3(256), 0, stream>>>(Pmax, Psum, lens, Pb);
        gemm_mfma<<<dim3((PM / 16) * (PD / 16)), dim3(256), 0, stream>>>(Pb, Wb, b, out);
    } else if (ws_size >= need_bf16) {
        unsigned short* Pb = (unsigned short*)d_ws;
        unsigned short* Wb = (unsigned short*)((char*)d_ws + pb_bytes);
        convert_w<<<dim3((PD * PK2) / (256 * 8)), dim3(256), 0, stream>>>(W, Wb);
        pool_kernel2<<<dim3(PM), dim3(1024), 0, stream>>>(doc, map, lens, Pb);
        gemm_mfma1<<<dim3((PM / 16) * (PD / 16)), dim3(64), 0, stream>>>(Pb, Wb, b, out);
    } else {
        fused_kernel<<<dim3(PM), dim3(256), 0, stream>>>(doc, map, lens, W, b, out);
    }
}

// Round 7
// 30.438 us; speedup vs baseline: 1.2496x; 1.1303x over previous
//
#include <hip/hip_runtime.h>
#include <hip/hip_bf16.h>
#include <math.h>

// Problem constants: N=4, E=64, L=512, D=768
#define PN 4
#define PE 64
#define PL 512
#define PD 768
#define PK2 (2 * PD)        // 1536
#define PM (PN * PE)        // 256 rows

#define EG 4                // entities per pool block
#define DCW 128             // d-columns per pool block
#define NDC (PD / DCW)      // 6 d-chunks
#define NPOOLB (PN * (PE / EG) * NDC)          // 384 pool blocks
#define NCVT ((PD * PK2) / (512 * 8))          // 288 W-convert blocks

using bf16x8 = __attribute__((ext_vector_type(8))) short;
using f32x4  = __attribute__((ext_vector_type(4))) float;

static __device__ __forceinline__ unsigned short f2bf(float x) {
    unsigned int u = __float_as_uint(x);
    unsigned int r = (u + 0x7FFFu + ((u >> 16) & 1u)) >> 16;   // RNE
    return (unsigned short)r;
}

// ---------------------------------------------------------------------------
// pool_full: ONE kernel, no global partials, no second pooling pass.
// Pool blocks (bid 0..383): (n, e-group of 4, d-chunk of 128).
//   512 threads = 8 waves. Wave w owns l in [w*64, w*64+64) -- all of L
//   covered in-block. Lane owns float2 at d = d0 + lane*2.
//   Masks: per wave, per entity: one 64-bit ballot over its own l-window
//   (wave-uniform SGPR). cand = bit ? v : 0  == entity_states elem EXACTLY,
//   so max needs no has_zero fixup (zeros are real candidates).
//   Cross-wave reduce: 32 KB LDS, deterministic tree; final phase divides
//   by lens and writes Pb bf16 directly.
// Convert blocks (bid 384..671): W f32 -> Wb bf16, 8 elems/thread.
// ---------------------------------------------------------------------------
__global__ __launch_bounds__(512) void pool_full(
    const float* __restrict__ doc,    // [N][L][D]
    const float* __restrict__ map,    // [N][E][L]
    const float* __restrict__ lens,   // [N][E]
    const float* __restrict__ W,      // [768][1536]
    unsigned short* __restrict__ Pb,  // [256][1536] bf16
    unsigned short* __restrict__ Wb)  // [768][1536] bf16
{
    const int bid = blockIdx.x;
    const int tid = threadIdx.x;

    if (bid >= NPOOLB) {
        // ---- W conversion blocks ----
        const size_t i = ((size_t)(bid - NPOOLB) * 512 + tid) * 8;
        const float4 a = *reinterpret_cast<const float4*>(W + i);
        const float4 c = *reinterpret_cast<const float4*>(W + i + 4);
        union { unsigned short s[8]; uint4 v; } r;
        r.s[0] = f2bf(a.x); r.s[1] = f2bf(a.y); r.s[2] = f2bf(a.z); r.s[3] = f2bf(a.w);
        r.s[4] = f2bf(c.x); r.s[5] = f2bf(c.y); r.s[6] = f2bf(c.z); r.s[7] = f2bf(c.w);
        *reinterpret_cast<uint4*>(Wb + i) = r.v;
        return;
    }

    __shared__ float2 lmax[8][EG][64];   // [wave][e][lane] -- 16 KB
    __shared__ float2 lsum[8][EG][64];   // 16 KB

    const int dc   = bid % NDC;
    const int rest = bid / NDC;
    const int eg   = rest & 15;          // 16 e-groups
    const int n    = rest >> 4;
    const int e0   = eg * EG;
    const int d0   = dc * DCW;
    const int w    = tid >> 6;
    const int lane = tid & 63;

    // per-wave 64-bit masks for its own l-window (SGPR, wave-uniform)
    unsigned long long mk[EG];
    #pragma unroll
    for (int e = 0; e < EG; ++e) {
        const float m = map[((size_t)n * PE + e0 + e) * PL + w * 64 + lane];
        mk[e] = __ballot(m != 0.0f);
    }

    // thread's float2 column: doc[n][w*64 + l][d0 + lane*2]
    const float2* docp = reinterpret_cast<const float2*>(
        doc + ((size_t)n * PL + w * 64) * PD + d0) + lane;

    float2 mx[EG], sm[EG];
    #pragma unroll
    for (int e = 0; e < EG; ++e) {
        mx[e] = make_float2(-INFINITY, -INFINITY);
        sm[e] = make_float2(0.f, 0.f);
    }

    #pragma unroll 8
    for (int l = 0; l < 64; ++l) {
        const float2 v = docp[(size_t)l * (PD / 2)];
        #pragma unroll
        for (int e = 0; e < EG; ++e) {
            const bool bit = (mk[e] >> l) & 1ull;   // wave-uniform (SALU)
            const float cx = bit ? v.x : 0.0f;      // exact entity_states elem
            const float cy = bit ? v.y : 0.0f;
            sm[e].x += cx;  sm[e].y += cy;
            mx[e].x = fmaxf(mx[e].x, cx);
            mx[e].y = fmaxf(mx[e].y, cy);
        }
    }

    #pragma unroll
    for (int e = 0; e < EG; ++e) {
        lmax[w][e][lane] = mx[e];
        lsum[w][e][lane] = sm[e];
    }
    __syncthreads();

    // final: 256 (e,lane) slots; tid<256 -> max, tid>=256 -> mean
    const int slot = tid & 255;
    const int e  = slot >> 6;
    const int ln = slot & 63;
    const int ne = n * PE + e0 + e;
    if (tid < 256) {
        float2 m = lmax[0][e][ln];
        #pragma unroll
        for (int ww = 1; ww < 8; ++ww) {
            const float2 t = lmax[ww][e][ln];
            m.x = fmaxf(m.x, t.x);
            m.y = fmaxf(m.y, t.y);
        }
        const unsigned int pk = (unsigned int)f2bf(m.x) | ((unsigned int)f2bf(m.y) << 16);
        *reinterpret_cast<unsigned int*>(Pb + (size_t)ne * PK2 + d0 + ln * 2) = pk;
    } else {
        float2 s = lsum[0][e][ln];
        #pragma unroll
        for (int ww = 1; ww < 8; ++ww) {
            const float2 t = lsum[ww][e][ln];
            s.x += t.x;
            s.y += t.y;
        }
        const float inv = 1.0f / lens[ne];
        const unsigned int pk = (unsigned int)f2bf(s.x * inv) | ((unsigned int)f2bf(s.y * inv) << 16);
        *reinterpret_cast<unsigned int*>(Pb + (size_t)ne * PK2 + PD + d0 + ln * 2) = pk;
    }
}

// ---------------------------------------------------------------------------
// GEMM via MFMA bf16 16x16x32, no LDS. out[r][d] = sum_k P[r][k]*W[d][k] + b[d]
// 768 single-wave blocks, one 16x16 tile each (R3-proven fast).
// ---------------------------------------------------------------------------
__global__ __launch_bounds__(64) void gemm_mfma1(
    const unsigned short* __restrict__ Pb,  // [256][1536] bf16
    const unsigned short* __restrict__ Wb,  // [768][1536] bf16
    const float* __restrict__ b,            // [768]
    float* __restrict__ out)                // [256][768]
{
    const int lane = threadIdx.x;
    const int tile = blockIdx.x;             // 0..767
    const int rt = tile & 15;                // M tile
    const int ct = tile >> 4;                // N tile
    const int r0 = rt * 16, d0 = ct * 16;

    const int fr = lane & 15;
    const int kg = lane >> 4;

    const unsigned short* pA = Pb + (size_t)(r0 + fr) * PK2 + kg * 8;
    const unsigned short* pB = Wb + (size_t)(d0 + fr) * PK2 + kg * 8;

    f32x4 acc = {0.f, 0.f, 0.f, 0.f};
    #pragma unroll 8
    for (int k0 = 0; k0 < PK2; k0 += 32) {
        const bf16x8 a  = *reinterpret_cast<const bf16x8*>(pA + k0);
        const bf16x8 bb = *reinterpret_cast<const bf16x8*>(pB + k0);
        acc = __builtin_amdgcn_mfma_f32_16x16x32_bf16(a, bb, acc, 0, 0, 0);
    }

    const int c = d0 + fr;
    const float bias = b[c];
    #pragma unroll
    for (int j = 0; j < 4; ++j)
        out[(size_t)(r0 + kg * 4 + j) * PD + c] = acc[j] + bias;
}

// ===========================================================================
// Fallback: fully fused f32 (R1-proven) -- used only if ws is tiny.
// ===========================================================================
__global__ __launch_bounds__(256) void fused_kernel(
    const float* __restrict__ doc, const float* __restrict__ map,
    const float* __restrict__ lens, const float* __restrict__ W,
    const float* __restrict__ b, float* __restrict__ out)
{
    __shared__ float Prow[PK2];
    const int ne = blockIdx.x, n = ne >> 6, t = threadIdx.x;
    const float* docn = doc + (size_t)n * PL * PD;
    const float* mrow = map + (size_t)ne * PL;
    float mx0=-INFINITY, mx1=-INFINITY, mx2=-INFINITY, s0=0.f, s1=0.f, s2=0.f;
    bool has_zero = false;
    for (int l = 0; l < PL; ++l) {
        const float m = mrow[l];
        if (m != 0.0f) {
            const float* dr = docn + (size_t)l * PD;
            const float a = dr[t], c = dr[t+256], e = dr[t+512];
            mx0=fmaxf(mx0,a); s0+=a; mx1=fmaxf(mx1,c); s1+=c; mx2=fmaxf(mx2,e); s2+=e;
        } else has_zero = true;
    }
    if (has_zero) { mx0=fmaxf(mx0,0.f); mx1=fmaxf(mx1,0.f); mx2=fmaxf(mx2,0.f); }
    const float invlen = 1.0f / lens[ne];
    Prow[t]=mx0; Prow[t+256]=mx1; Prow[t+512]=mx2;
    Prow[PD+t]=s0*invlen; Prow[PD+t+256]=s1*invlen; Prow[PD+t+512]=s2*invlen;
    __syncthreads();
    #pragma unroll
    for (int i = 0; i < 3; ++i) {
        const int d = t + i*256;
        const float* wrow = W + (size_t)d * PK2;
        float acc = 0.f;
        for (int k = 0; k < PK2; k += 4) {
            const float4 w = *reinterpret_cast<const float4*>(&wrow[k]);
            acc += Prow[k]*w.x + Prow[k+1]*w.y + Prow[k+2]*w.z + Prow[k+3]*w.w;
        }
        out[(size_t)ne * PD + d] = acc + b[d];
    }
}

extern "C" void kernel_launch(void* const* d_in, const int* in_sizes, int n_in,
                              void* d_out, int out_size, void* d_ws, size_t ws_size,
                              hipStream_t stream) {
    const float* doc  = (const float*)d_in[0];   // (4,512,768)
    const float* map  = (const float*)d_in[1];   // (4,64,512)
    const float* lens = (const float*)d_in[2];   // (4,64)
    const float* W    = (const float*)d_in[3];   // (768,1536)
    const float* b    = (const float*)d_in[4];   // (768,)
    float* out = (float*)d_out;                  // (4,64,768)

    const size_t pb_bytes = (size_t)PM * PK2 * sizeof(unsigned short);   // 768 KiB
    const size_t wb_bytes = (size_t)PD * PK2 * sizeof(unsigned short);   // 2.25 MiB
    const size_t need     = pb_bytes + wb_bytes;                         // 3 MiB

    if (ws_size >= need) {
        unsigned short* Pb = (unsigned short*)d_ws;
        unsigned short* Wb = (unsigned short*)((char*)d_ws + pb_bytes);
        pool_full<<<dim3(NPOOLB + NCVT), dim3(512), 0, stream>>>(
            doc, map, lens, W, Pb, Wb);
        gemm_mfma1<<<dim3((PM / 16) * (PD / 16)), dim3(64), 0, stream>>>(Pb, Wb, b, out);
    } else {
        fused_kernel<<<dim3(PM), dim3(256), 0, stream>>>(doc, map, lens, W, b, out);
    }
}